// Round 8
// baseline (156.625 us; speedup 1.0000x reference)
//
#include <hip/hip_runtime.h>
#include <hip/hip_bf16.h>

#define DEV __device__ __forceinline__

typedef __attribute__((ext_vector_type(8))) short bf16x8;
typedef __attribute__((ext_vector_type(4))) float f32x4;

constexpr int Bq = 16, Lq = 2048, Dq = 128;
constexpr int RZ = 2 * Dq;            // 256
constexpr float L2E = 1.4426950408889634f;   // log2(e)

DEV float exp2f_hw(float x) { return __builtin_amdgcn_exp2f(x); }  // v_exp_f32

DEV unsigned short f2bf(float f) {
    union { __hip_bfloat16 h; unsigned short u; } v;
    v.h = __float2bfloat16(f);
    return v.u;
}
DEV float bfu_lo(int u) { return __uint_as_float((unsigned)u << 16); }
DEV float bfu_hi(int u) { return __uint_as_float((unsigned)u & 0xffff0000u); }

// sigmoid(x) given y = x*log2e :  1/(1+2^-y)
DEV float sigm2(float y) { return __builtin_amdgcn_rcpf(1.f + exp2f_hw(-y)); }
// tanh(v) given y = 2v*log2e :  1 - 2/(2^y + 1)
DEV float tanh2(float y) {
    float e = exp2f_hw(y);
    return fmaf(-2.f, __builtin_amdgcn_rcpf(e + 1.f), 1.f);
}

DEV bf16x8 pack8s(float4 a, float4 b, float s) {
    bf16x8 r;
    r[0] = (short)f2bf(a.x * s); r[1] = (short)f2bf(a.y * s);
    r[2] = (short)f2bf(a.z * s); r[3] = (short)f2bf(a.w * s);
    r[4] = (short)f2bf(b.x * s); r[5] = (short)f2bf(b.y * s);
    r[6] = (short)f2bf(b.z * s); r[7] = (short)f2bf(b.w * s);
    return r;
}
DEV int2 packbf4(float a, float b, float c, float d) {
    int2 r;
    r.x = (int)(((unsigned)f2bf(b) << 16) | (unsigned)f2bf(a));
    r.y = (int)(((unsigned)f2bf(d) << 16) | (unsigned)f2bf(c));
    return r;
}

// ---------------------------------------------------------------------------
// Kernel 1: gate pre-projection into TRANSPOSED layout
//   XpT[b][g4][l]  (g4 in [0,96): 4-unit bf16 group = 8B element; l in [0,2048))
//   value = ((x[b][l] @ W_ih^T)[g] + bias[g]) * scale[g]
//   rows g 0..255 (r,z): bias b_ih+b_hh, scale log2e; 256..383 (n): b_ih, 2*log2e.
//   Consumer reads 8B per lane with l varying across lanes -> coalesced.
// ---------------------------------------------------------------------------
__global__ __launch_bounds__(512, 2) void k_proj(
    const float* __restrict__ x, const float* __restrict__ W_ih,
    const float* __restrict__ b_ih, const float* __restrict__ b_hh,
    unsigned short* __restrict__ XpT)
{
    __shared__ __attribute__((aligned(16))) unsigned char lds[96 * 64 * 8]; // 48KB

    const int tid = threadIdx.x;
    const int lane = tid & 63, w = tid >> 6;      // w in [0,8)
    const int l15 = lane & 15, l4 = lane >> 4;
    const int r0 = blockIdx.x * 64;               // global x-row base

    // stage x tile -> bf16 swizzled LDS (first 16KB)
#pragma unroll
    for (int it = 0; it < 4; ++it) {
        int c = it * 512 + tid;           // 16B fp32 chunk, 2048 total
        int byte = c << 4;
        int row = byte >> 9;
        int wb = byte & 511;
        float4 v = *(const float4*)((const char*)(x + (size_t)r0 * Dq) + byte);
        int dst = row * 256 + ((wb >> 1) ^ ((row & 7) << 4));
        *(int2*)(lds + dst) = packbf4(v.x, v.y, v.z, v.w);
    }

    // A-fragments: W_ih rows [48w, 48w+48)
    bf16x8 afr[3][4];
#pragma unroll
    for (int mt = 0; mt < 3; ++mt)
#pragma unroll
        for (int kc = 0; kc < 4; ++kc) {
            int row = 48 * w + 16 * mt + l15;
            int k0 = 32 * kc + 8 * l4;
            const float* p = W_ih + row * Dq + k0;
            afr[mt][kc] = pack8s(*(const float4*)p, *(const float4*)(p + 4), 1.f);
        }
    float fs[3], bias[3][4];
#pragma unroll
    for (int mt = 0; mt < 3; ++mt) {
        int rbase = 48 * w + 16 * mt + 4 * l4;
        fs[mt] = (rbase < RZ) ? L2E : 2.f * L2E;
#pragma unroll
        for (int r = 0; r < 4; ++r) {
            int row = rbase + r;
            float bv = b_ih[row] + (row < RZ ? b_hh[row] : 0.f);
            bias[mt][r] = bv * fs[mt];
        }
    }
    __syncthreads();

    f32x4 acc[3][4];
#pragma unroll
    for (int mt = 0; mt < 3; ++mt)
#pragma unroll
        for (int nt = 0; nt < 4; ++nt) {
            acc[mt][nt][0] = 0.f; acc[mt][nt][1] = 0.f;
            acc[mt][nt][2] = 0.f; acc[mt][nt][3] = 0.f;
        }

#pragma unroll
    for (int kc = 0; kc < 4; ++kc) {
        bf16x8 bfr[4];
#pragma unroll
        for (int nt = 0; nt < 4; ++nt) {
            int row = 16 * nt + l15;
            int off = row * 256 + ((64 * kc + 16 * l4) ^ ((row & 7) << 4));
            bfr[nt] = *(const bf16x8*)(lds + off);
        }
#pragma unroll
        for (int nt = 0; nt < 4; ++nt)
#pragma unroll
            for (int mt = 0; mt < 3; ++mt)
                acc[mt][nt] = __builtin_amdgcn_mfma_f32_16x16x32_bf16(
                    afr[mt][kc], bfr[nt], acc[mt][nt], 0, 0, 0);
    }

    __syncthreads();  // x-stage reads done; reuse lds as [96 g4][64 l] int2 tile

#pragma unroll
    for (int mt = 0; mt < 3; ++mt)
#pragma unroll
        for (int nt = 0; nt < 4; ++nt) {
            int r = 16 * nt + l15;             // local l
            int g4 = 12 * w + 4 * mt + l4;     // unit-group
            int2 pk = packbf4(fmaf(acc[mt][nt][0], fs[mt], bias[mt][0]),
                              fmaf(acc[mt][nt][1], fs[mt], bias[mt][1]),
                              fmaf(acc[mt][nt][2], fs[mt], bias[mt][2]),
                              fmaf(acc[mt][nt][3], fs[mt], bias[mt][3]));
            *(int2*)(lds + (((g4 << 6) + r) << 3)) = pk;
        }
    __syncthreads();

    // transposed copy-out: 96 chunks of 64 elements x 8B (512B each, coalesced)
    {
        const int lr0 = r0 & 2047;
        const int bb = r0 >> 11;
#pragma unroll
        for (int it = 0; it < 6; ++it) {
            int idx = it * 512 + tid;          // int4 index in [0,3072)
            int g4 = idx >> 5, off = idx & 31;
            size_t d = (((size_t)(bb * 96 + g4) << 11) + lr0) >> 1;  // int4 units
            ((int4*)XpT)[d + off] = ((const int4*)lds)[idx];
        }
    }
}

// ---------------------------------------------------------------------------
// Kernel 2: fused local GRU.  Block = 32 windows, 8 waves (grid 1024 ->
// 4 blocks/CU, 32 waves/CU).  Wave owns 16 units/gate, nt=2 window tiles.
// Gate inputs read directly from global XpT (coalesced, L2-resident) at the
// top of each step, consumed after the MFMA block.  h fp32 in registers,
// republished bf16 to double-buffered hls (16KB LDS), 1 barrier/step.
// t=0 peeled.  (512,2) -> no spills.
// ---------------------------------------------------------------------------
__global__ __launch_bounds__(512, 2) void k_rnn(
    const int2* __restrict__ Xp2, const float* __restrict__ W_hh,
    const float* __restrict__ b_ih, const float* __restrict__ b_hh,
    float* __restrict__ out)
{
    __shared__ __attribute__((aligned(16))) unsigned char hls[2 * 32 * 256]; // 16KB

    const int tid = threadIdx.x;
    const int lane = tid & 63, w = tid >> 6;
    const int l15 = lane & 15, l4 = lane >> 4;
    const int b = blockIdx.x >> 6;
    const int l0 = (blockIdx.x & 63) << 5;

    // A fragments: W_hh row = 128*g + 16*w + l15, scaled by gate factor
    bf16x8 afr[3][4];
#pragma unroll
    for (int g = 0; g < 3; ++g) {
        float fg = (g < 2) ? L2E : 2.f * L2E;
#pragma unroll
        for (int kc = 0; kc < 4; ++kc) {
            int row = 128 * g + 16 * w + l15;
            int k0 = 32 * kc + 8 * l4;
            const float* p = W_hh + row * Dq + k0;
            afr[g][kc] = pack8s(*(const float4*)p, *(const float4*)(p + 4), fg);
        }
    }
    const int u0 = 16 * w + 4 * l4;
    const float4 bir = *(const float4*)(b_ih + u0);
    const float4 bhr = *(const float4*)(b_hh + u0);
    const float4 biz = *(const float4*)(b_ih + Dq + u0);
    const float4 bhz = *(const float4*)(b_hh + Dq + u0);
    const float4 bin_ = *(const float4*)(b_ih + RZ + u0);
    const float4 bhn = *(const float4*)(b_hh + RZ + u0);
    f32x4 bhn4;
    bhn4[0] = bhn.x * (2.f * L2E); bhn4[1] = bhn.y * (2.f * L2E);
    bhn4[2] = bhn.z * (2.f * L2E); bhn4[3] = bhn.w * (2.f * L2E);
    // packed bf16 pad gate-inputs for l < 0 rows
    const int2 pbr = packbf4((bir.x + bhr.x) * L2E, (bir.y + bhr.y) * L2E,
                             (bir.z + bhr.z) * L2E, (bir.w + bhr.w) * L2E);
    const int2 pbz = packbf4((biz.x + bhz.x) * L2E, (biz.y + bhz.y) * L2E,
                             (biz.z + bhz.z) * L2E, (biz.w + bhz.w) * L2E);
    const int2 pbn = packbf4(bin_.x * (2.f * L2E), bin_.y * (2.f * L2E),
                             bin_.z * (2.f * L2E), bin_.w * (2.f * L2E));

    // transposed gate-input base pointers (8B elements), row l = l0 + l15 - 7 + (16nt + t)
    const size_t rowr = ((size_t)(b * 96) + (u0 >> 2)) << 11;
    const int2* pr = Xp2 + rowr + (l0 + l15 - 7);
    const int2* pz = pr + (size_t)32 * 2048;
    const int2* pn = pr + (size_t)64 * 2048;
    const bool edge = (l0 == 0);

    f32x4 h[2];

    // ---- t = 0 (h0 == 0: gates from XpT only) ----
#pragma unroll
    for (int nt = 0; nt < 2; ++nt) {
        int2 qr, qz, qn;
        if (!edge) {
            qr = pr[16 * nt]; qz = pz[16 * nt]; qn = pn[16 * nt];
        } else {
            int ln = 16 * nt + l15 - 7;
            int lnc = ln < 0 ? 0 : ln;
            qr = (Xp2 + rowr)[lnc];
            qz = (Xp2 + rowr + (size_t)32 * 2048)[lnc];
            qn = (Xp2 + rowr + (size_t)64 * 2048)[lnc];
            if (ln < 0) { qr = pbr; qz = pbz; qn = pbn; }
        }
        float xr[4] = {bfu_lo(qr.x), bfu_hi(qr.x), bfu_lo(qr.y), bfu_hi(qr.y)};
        float xz[4] = {bfu_lo(qz.x), bfu_hi(qz.x), bfu_lo(qz.y), bfu_hi(qz.y)};
        float xn[4] = {bfu_lo(qn.x), bfu_hi(qn.x), bfu_lo(qn.y), bfu_hi(qn.y)};
#pragma unroll
        for (int r = 0; r < 4; ++r) {
            float rv = sigm2(xr[r]);
            float zv = sigm2(xz[r]);
            float nv = tanh2(fmaf(rv, bhn4[r], xn[r]));
            h[nt][r] = nv - zv * nv;   // h_prev = 0
        }
    }
#pragma unroll
    for (int nt = 0; nt < 2; ++nt) {
        int win = 16 * nt + l15;
        int off = win * 256 + ((2 * u0) ^ ((win & 7) << 4));   // buffer 0
        *(int2*)(hls + off) = packbf4(h[nt][0], h[nt][1], h[nt][2], h[nt][3]);
    }
    __syncthreads();

    // ---- t = 1..7 : one barrier per step, loads issued at top ----
    for (int t = 1; t < 8; ++t) {
        int2 qr_s[2], qz_s[2], qn_s[2];
        if (!edge) {
#pragma unroll
            for (int nt = 0; nt < 2; ++nt) {
                qr_s[nt] = pr[16 * nt + t];
                qz_s[nt] = pz[16 * nt + t];
                qn_s[nt] = pn[16 * nt + t];
            }
        } else {
#pragma unroll
            for (int nt = 0; nt < 2; ++nt) {
                int ln = 16 * nt + l15 + t - 7;
                int lnc = ln < 0 ? 0 : ln;
                qr_s[nt] = (Xp2 + rowr)[lnc];
                qz_s[nt] = (Xp2 + rowr + (size_t)32 * 2048)[lnc];
                qn_s[nt] = (Xp2 + rowr + (size_t)64 * 2048)[lnc];
                if (ln < 0) { qr_s[nt] = pbr; qz_s[nt] = pbz; qn_s[nt] = pbn; }
            }
        }

        const int rdo = ((t - 1) & 1) << 13;
        const int wro = (t & 1) << 13;
        f32x4 ar[2], az[2], an[2];
#pragma unroll
        for (int nt = 0; nt < 2; ++nt) {
            ar[nt][0] = 0.f; ar[nt][1] = 0.f; ar[nt][2] = 0.f; ar[nt][3] = 0.f;
            az[nt] = ar[nt];
            an[nt] = bhn4;
        }
#pragma unroll
        for (int kc = 0; kc < 4; ++kc) {
            bf16x8 bfr[2];
#pragma unroll
            for (int nt = 0; nt < 2; ++nt) {
                int win = 16 * nt + l15;
                int off = rdo + win * 256 + ((64 * kc + 16 * l4) ^ ((win & 7) << 4));
                bfr[nt] = *(const bf16x8*)(hls + off);
            }
#pragma unroll
            for (int nt = 0; nt < 2; ++nt) {
                ar[nt] = __builtin_amdgcn_mfma_f32_16x16x32_bf16(afr[0][kc], bfr[nt], ar[nt], 0, 0, 0);
                az[nt] = __builtin_amdgcn_mfma_f32_16x16x32_bf16(afr[1][kc], bfr[nt], az[nt], 0, 0, 0);
                an[nt] = __builtin_amdgcn_mfma_f32_16x16x32_bf16(afr[2][kc], bfr[nt], an[nt], 0, 0, 0);
            }
        }
#pragma unroll
        for (int nt = 0; nt < 2; ++nt) {
            float xr[4] = {bfu_lo(qr_s[nt].x), bfu_hi(qr_s[nt].x),
                           bfu_lo(qr_s[nt].y), bfu_hi(qr_s[nt].y)};
            float xz[4] = {bfu_lo(qz_s[nt].x), bfu_hi(qz_s[nt].x),
                           bfu_lo(qz_s[nt].y), bfu_hi(qz_s[nt].y)};
            float xn[4] = {bfu_lo(qn_s[nt].x), bfu_hi(qn_s[nt].x),
                           bfu_lo(qn_s[nt].y), bfu_hi(qn_s[nt].y)};
#pragma unroll
            for (int r = 0; r < 4; ++r) {
                float rv = sigm2(ar[nt][r] + xr[r]);
                float zv = sigm2(az[nt][r] + xz[r]);
                float nv = tanh2(fmaf(rv, an[nt][r], xn[r]));
                h[nt][r] = nv + zv * (h[nt][r] - nv);
            }
        }
        if (t < 7) {
#pragma unroll
            for (int nt = 0; nt < 2; ++nt) {
                int win = 16 * nt + l15;
                int off = wro + win * 256 + ((2 * u0) ^ ((win & 7) << 4));
                *(int2*)(hls + off) = packbf4(h[nt][0], h[nt][1], h[nt][2], h[nt][3]);
            }
            __syncthreads();
        }
    }

    // epilogue: h (fp32) -> out[b][l][u]
#pragma unroll
    for (int nt = 0; nt < 2; ++nt) {
        size_t idx = ((size_t)(b * Lq + l0 + 16 * nt + l15)) * Dq + u0;
        *(f32x4*)(out + idx) = h[nt];
    }
}

extern "C" void kernel_launch(void* const* d_in, const int* in_sizes, int n_in,
                              void* d_out, int out_size, void* d_ws, size_t ws_size,
                              hipStream_t stream) {
    const float* x    = (const float*)d_in[0];
    const float* W_ih = (const float*)d_in[1];
    const float* W_hh = (const float*)d_in[2];
    const float* b_ih = (const float*)d_in[3];
    const float* b_hh = (const float*)d_in[4];
    float* out = (float*)d_out;
    unsigned short* XpT = (unsigned short*)d_ws;  // [16][96][2048] x 8B = 25.2 MB

    k_proj<<<dim3(512), dim3(512), 0, stream>>>(x, W_ih, b_ih, b_hh, XpT);
    k_rnn<<<dim3(1024), dim3(512), 0, stream>>>((const int2*)XpT, W_hh, b_ih, b_hh, out);
}